// Round 4
// baseline (1138.121 us; speedup 1.0000x reference)
//
#include <hip/hip_runtime.h>
#include <hip/hip_bf16.h>
#include <math.h>
#include <stdint.h>

#define D_MODEL 2048
#define D_FF    8192
#define MTOK    16384   // 4 * 4096 tokens
#define NW      (D_FF * D_MODEL)   // elements per weight matrix

typedef int    i32x4  __attribute__((ext_vector_type(4)));
typedef __bf16 bf16x8 __attribute__((ext_vector_type(8)));

// width-16 async global->LDS (per-lane global addr, wave-uniform LDS base + lane*16)
#define GLOAD_LDS16(gp, lp)                                                   \
  __builtin_amdgcn_global_load_lds(                                           \
      (__attribute__((address_space(1))) void*)(gp),                          \
      (__attribute__((address_space(3))) void*)(lp), 16, 0, 0)

// ---------------- stage 1: deterministic double partial sums of |w| ----------------
__global__ void absum_s1(const float* __restrict__ w1, const float* __restrict__ w2,
                         double* __restrict__ partials) {
    const float* w = blockIdx.y ? w2 : w1;
    __shared__ double sm[256];
    int tid = blockIdx.x * 256 + threadIdx.x;
    double s = 0.0;
    for (int i = tid; i < NW / 4; i += 1024 * 256) {
        float4 v = ((const float4*)w)[i];
        s += (double)fabsf(v.x) + (double)fabsf(v.y) + (double)fabsf(v.z) + (double)fabsf(v.w);
    }
    sm[threadIdx.x] = s;
    __syncthreads();
    for (int off = 128; off > 0; off >>= 1) {
        if (threadIdx.x < off) sm[threadIdx.x] += sm[threadIdx.x + off];
        __syncthreads();
    }
    if (threadIdx.x == 0) partials[blockIdx.y * 1024 + blockIdx.x] = sm[0];
}

// ---------------- stage 2: 1024 partials -> float threshold 0.7*mean ----------------
__global__ void absum_s2(const double* __restrict__ partials, float* __restrict__ thr) {
    __shared__ double sm[256];
    for (int wsel = 0; wsel < 2; ++wsel) {
        const double* p = partials + wsel * 1024;
        double s = p[threadIdx.x] + p[threadIdx.x + 256] + p[threadIdx.x + 512] + p[threadIdx.x + 768];
        sm[threadIdx.x] = s;
        __syncthreads();
        for (int off = 128; off > 0; off >>= 1) {
            if (threadIdx.x < off) sm[threadIdx.x] += sm[threadIdx.x + off];
            __syncthreads();
        }
        if (threadIdx.x == 0) thr[wsel] = (float)(0.7 * (sm[0] / (double)NW));
        __syncthreads();
    }
}

// ---------------- w1 -> ternary i8, elementwise ----------------
__global__ void quantw1(const float* __restrict__ w, const float* __restrict__ thr,
                        int8_t* __restrict__ q) {
    float t = thr[0];
    int i = (blockIdx.x * 256 + threadIdx.x) * 4;
    float4 v = *(const float4*)(w + i);
    char4 o;
    o.x = (fabsf(v.x) >= t) ? (v.x > 0.f ? 1 : -1) : 0;
    o.y = (fabsf(v.y) >= t) ? (v.y > 0.f ? 1 : -1) : 0;
    o.z = (fabsf(v.z) >= t) ? (v.z > 0.f ? 1 : -1) : 0;
    o.w = (fabsf(v.w) >= t) ? (v.w > 0.f ? 1 : -1) : 0;
    *(char4*)(q + i) = o;
}

// ---------------- w2 -> ternary i8, one block per row, + row sums (colsum) ---------
__global__ void quantw2(const float* __restrict__ w, const float* __restrict__ thr,
                        int8_t* __restrict__ q, float* __restrict__ colsum) {
    __shared__ int sm[256];
    float t = thr[1];
    const int row = blockIdx.x;
    const int tid = threadIdx.x;
    int isum = 0;
    #pragma unroll
    for (int j = 0; j < 8; ++j) {
        int idx = row * D_FF + j * 1024 + tid * 4;
        float4 v = *(const float4*)(w + idx);
        char4 o;
        o.x = (fabsf(v.x) >= t) ? (v.x > 0.f ? 1 : -1) : 0;
        o.y = (fabsf(v.y) >= t) ? (v.y > 0.f ? 1 : -1) : 0;
        o.z = (fabsf(v.z) >= t) ? (v.z > 0.f ? 1 : -1) : 0;
        o.w = (fabsf(v.w) >= t) ? (v.w > 0.f ? 1 : -1) : 0;
        isum += o.x + o.y + o.z + o.w;
        *(char4*)(q + idx) = o;
    }
    sm[tid] = isum;
    __syncthreads();
    for (int off = 128; off > 0; off >>= 1) {
        if (tid < off) sm[tid] += sm[tid + off];
        __syncthreads();
    }
    if (tid == 0) colsum[row] = (float)sm[0];
}

// ---------------- x -> per-row symmetric i8, one block per token row ----------------
__global__ void xquant(const float* __restrict__ x, int8_t* __restrict__ xq,
                       float* __restrict__ sx) {
    __shared__ float sm[256];
    const int row = blockIdx.x;
    const int tid = threadIdx.x;
    float4 v[2];
    float mx = 0.f;
    #pragma unroll
    for (int j = 0; j < 2; ++j) {
        v[j] = *(const float4*)(x + (size_t)row * D_MODEL + j * 1024 + tid * 4);
        mx = fmaxf(mx, fmaxf(fmaxf(fabsf(v[j].x), fabsf(v[j].y)),
                             fmaxf(fabsf(v[j].z), fabsf(v[j].w))));
    }
    sm[tid] = mx;
    __syncthreads();
    for (int off = 128; off > 0; off >>= 1) {
        if (tid < off) sm[tid] = fmaxf(sm[tid], sm[tid + off]);
        __syncthreads();
    }
    float m = sm[0];
    float inv = (m > 0.f) ? 127.f / m : 0.f;
    if (tid == 0) sx[row] = (m > 0.f) ? m / 127.f : 0.f;
    #pragma unroll
    for (int j = 0; j < 2; ++j) {
        char4 o;
        o.x = (int8_t)min(127, max(-127, __float2int_rn(v[j].x * inv)));
        o.y = (int8_t)min(127, max(-127, __float2int_rn(v[j].y * inv)));
        o.z = (int8_t)min(127, max(-127, __float2int_rn(v[j].z * inv)));
        o.w = (int8_t)min(127, max(-127, __float2int_rn(v[j].w * inv)));
        *(char4*)(xq + (size_t)row * D_MODEL + j * 1024 + tid * 4) = o;
    }
}

// ---------------- gelu(h) bf16 -> per-row ASYMMETRIC i8 (zero-point via colsum) -----
__global__ void hquant(const __bf16* __restrict__ h, int8_t* __restrict__ hq,
                       float2* __restrict__ sh) {
    __shared__ float sm[256];
    const int row = blockIdx.x;
    const int tid = threadIdx.x;
    const float gmin = -0.17f;
    float vals[4][8];
    float mx = -1e30f;
    #pragma unroll
    for (int j = 0; j < 4; ++j) {
        bf16x8 b = *(const bf16x8*)(h + (size_t)row * D_FF + j * 2048 + tid * 8);
        #pragma unroll
        for (int e = 0; e < 8; ++e) {
            float f = (float)b[e];
            vals[j][e] = f;
            mx = fmaxf(mx, f);
        }
    }
    sm[tid] = mx;
    __syncthreads();
    for (int off = 128; off > 0; off >>= 1) {
        if (tid < off) sm[tid] = fmaxf(sm[tid], sm[tid + off]);
        __syncthreads();
    }
    float M = sm[0];
    float s = (M - gmin) / 254.f;
    float inv = 254.f / (M - gmin);
    if (tid == 0) sh[row] = make_float2(s, 127.f * s + gmin);
    #pragma unroll
    for (int j = 0; j < 4; ++j) {
        char4 o0, o1;
        int q[8];
        #pragma unroll
        for (int e = 0; e < 8; ++e)
            q[e] = min(127, max(-127, __float2int_rn((vals[j][e] - gmin) * inv) - 127));
        o0.x = q[0]; o0.y = q[1]; o0.z = q[2]; o0.w = q[3];
        o1.x = q[4]; o1.y = q[5]; o1.z = q[6]; o1.w = q[7];
        int8_t* p = hq + (size_t)row * D_FF + j * 2048 + tid * 8;
        *(char4*)p = o0;
        *(char4*)(p + 4) = o1;
    }
}

// ===================================================================================
// 256x128 i8 MFMA GEMM, 4 waves x 128x64 per wave (LDS-pipe fix: arithmetic intensity).
//   C = A[M,K] * B[N,K]^T ; 256 threads = 4 waves (2M x 2N), per-wave 128x64 output.
//   Per K-half (BK=64), per wave: 12 ds_read_b128 feed 32 MFMA (85 ops/LDS-byte;
//   R2's 64x64 waves were 8 reads / 16 MFMA = 64 ops/B, which oversubscribed the
//   LDS pipe: 1542 cyc LDS vs 1310 cyc MFMA per CU -> MfmaUtil capped ~45%, got 29%).
//   New balance per CU half-pair: LDS 1156 cyc < MFMA 1310 cyc -> matrix pipe binds.
//   LDS ring-3 of 24 KiB stages (A 256x64, B 128x64) = 72 KiB -> 2 blocks/CU; regs
//   ~200/wave < 256 -> 2 waves/SIMD, one from each block, NOT barrier-synced ->
//   cross-block overlap of ds_read storms with MFMA clusters.
//   Per half: 6 gloads/thread (stage s+2), counted s_waitcnt vmcnt(6), ONE s_barrier.
//   16B chunk c of row r stored at slot c^((r>>1)&3): frag reads 2-way = free (R2: 0).
// EPI==0 (fc1): h[m,n] = bf16( gelu( rs[m] * acc + bias[n] ) )
// EPI==1 (fc2): out = rs2[m].x * acc + rs2[m].y * colsum[n] + bias[n]
// Both use the XCD-burst map: XCD owns 8 by-rows, iterated in 4-by bursts bx-major
// (B panel L2-reused 4x back-to-back; fc1's old map re-streamed w1q ~8x -> 557 MB).
// ===================================================================================
template<int EPI>
__global__ __launch_bounds__(256, 2) void gemm_i8_bt(
    const int8_t* __restrict__ A,    // [M,K]
    const int8_t* __restrict__ B,    // [N,K]
    const float*  __restrict__ bias, // [N]
    const float*  __restrict__ rs,   // fc1: sx[M] ; fc2: (float2*)sh[M]
    const float*  __restrict__ colsum, // fc2 only: [N]
    void* __restrict__ Cout,
    int M, int N, int K)
{
    __shared__ int8_t Sh[3 * 24576];   // ring-3: per stage A[256][64] + B[128][64]

    const int tid  = threadIdx.x;
    const int wave = tid >> 6;
    const int lane = tid & 63;
    const int quad = lane >> 4;
    const int l15  = lane & 15;
    const int wm   = (wave >> 1) * 128;   // 2 wave-rows of M (128 each)
    const int wn   = (wave & 1) * 64;     // 2 wave-cols of N (64 each)

    // ---- block -> tile map: XCD x owns by in [x*8,x*8+8), 4-by bursts, bx-major ----
    const int gx   = gridDim.x;           // fc1: 64, fc2: 16
    const int orig = blockIdx.y * gx + blockIdx.x;
    const int xcd  = orig & 7;
    const int l    = orig >> 3;
    const int stsh = (EPI == 0) ? 8 : 6;  // log2(4*gx)
    const int st   = l >> stsh;           // supertile (2 per XCD)
    const int r    = l & ((1 << stsh) - 1);
    const int by   = xcd * 8 + st * 4 + (r & 3);
    const int bx   = r >> 2;
    const int m0 = by << 8;   // *256
    const int n0 = bx << 7;   // *128

    i32x4 acc[8][4] = {};

    // ---- staging: per K-half, A = 1024 16B chunks (4/thread), B = 512 (2/thread) ----
    // A slot = it*256+tid (it<4): row = slot>>2, chunk cg = (slot&3)^((row>>1)&3)
    // B slot = it*256+tid (it<2): row = slot>>2 in [0,128)
    const int8_t* gA[4]; const int8_t* gB[2];
    #pragma unroll
    for (int it = 0; it < 4; ++it) {
        int slot = it * 256 + tid;
        int row  = slot >> 2;
        int cg   = (slot & 3) ^ ((row >> 1) & 3);
        gA[it] = A + (size_t)(m0 + row) * K + cg * 16;
    }
    #pragma unroll
    for (int it = 0; it < 2; ++it) {
        int slot = it * 256 + tid;
        int row  = slot >> 2;
        int cg   = (slot & 3) ^ ((row >> 1) & 3);
        gB[it] = B + (size_t)(n0 + row) * K + cg * 16;
    }
    char* const ldsb = (char*)Sh;
    char* dA[4]; char* dB[2];
    #pragma unroll
    for (int it = 0; it < 4; ++it) dA[it] = ldsb + it * 4096 + wave * 1024;
    #pragma unroll
    for (int it = 0; it < 2; ++it) dB[it] = ldsb + 16384 + it * 4096 + wave * 1024;

    // ---- per-thread fragment LDS offsets (within a stage) ----
    int aoff[8], boff[4];
    #pragma unroll
    for (int f = 0; f < 8; ++f) {
        int ra = wm + f * 16 + l15;
        aoff[f] = ra * 64 + ((quad ^ ((ra >> 1) & 3)) << 4);
    }
    #pragma unroll
    for (int f = 0; f < 4; ++f) {
        int rb = wn + f * 16 + l15;
        boff[f] = 16384 + rb * 64 + ((quad ^ ((rb >> 1) & 3)) << 4);
    }

    const int NH = K >> 6;   // BK=64 halves (fc1: 32, fc2: 128)
    const int STG = 24576;

    // ---- prologue: stage halves 0,1 (12 loads/thread); wait half 0 (6 outstanding) --
    #pragma unroll
    for (int h = 0; h < 2; ++h) {
        #pragma unroll
        for (int it = 0; it < 4; ++it) { GLOAD_LDS16(gA[it], dA[it] + h * STG); gA[it] += 64; }
        #pragma unroll
        for (int it = 0; it < 2; ++it) { GLOAD_LDS16(gB[it], dB[it] + h * STG); gB[it] += 64; }
    }
    asm volatile("s_waitcnt vmcnt(6)" ::: "memory");
    __builtin_amdgcn_s_barrier();
    __builtin_amdgcn_sched_barrier(0);

    int roff = 0;             // stage being read   (s % 3) * STG
    int soff = 2 * STG;       // stage being filled ((s+2) % 3) * STG

    for (int s = 0; s < NH; ++s) {
        // issue next-next stage loads first (earliest HBM start)
        if (s + 2 < NH) {
            #pragma unroll
            for (int it = 0; it < 4; ++it) { GLOAD_LDS16(gA[it], dA[it] + soff); gA[it] += 64; }
            #pragma unroll
            for (int it = 0; it < 2; ++it) { GLOAD_LDS16(gB[it], dB[it] + soff); gB[it] += 64; }
        }
        i32x4 bfr[4], afr[8];
        #pragma unroll
        for (int f = 0; f < 4; ++f) bfr[f] = *(const i32x4*)(ldsb + roff + boff[f]);
        #pragma unroll
        for (int f = 0; f < 8; ++f) afr[f] = *(const i32x4*)(ldsb + roff + aoff[f]);
        __builtin_amdgcn_s_setprio(1);
        #pragma unroll
        for (int mf = 0; mf < 8; ++mf)
            #pragma unroll
            for (int nf = 0; nf < 4; ++nf)
                acc[mf][nf] = __builtin_amdgcn_mfma_i32_16x16x64_i8(
                    afr[mf], bfr[nf], acc[mf][nf], 0, 0, 0);
        __builtin_amdgcn_s_setprio(0);
        // counted boundary: stage s+1 must be landed; keep stage s+2 (6 loads) in flight
        if (s < NH - 2)       { asm volatile("s_waitcnt vmcnt(6)" ::: "memory"); }
        else if (s == NH - 2) { asm volatile("s_waitcnt vmcnt(0)" ::: "memory"); }
        __builtin_amdgcn_sched_barrier(0);
        __builtin_amdgcn_s_barrier();
        __builtin_amdgcn_sched_barrier(0);
        roff = (roff == 2 * STG) ? 0 : roff + STG;
        soff = (soff == 2 * STG) ? 0 : soff + STG;
    }

    // ---- epilogue: C/D layout col = lane&15, row = quad*4 + r ----
    #pragma unroll
    for (int nf = 0; nf < 4; ++nf) {
        const int n = n0 + wn + nf * 16 + l15;
        const float bv = bias[n];
        const float cs = (EPI == 1) ? colsum[n] : 0.f;
        #pragma unroll
        for (int mf = 0; mf < 8; ++mf)
            #pragma unroll
            for (int r = 0; r < 4; ++r) {
                int m = m0 + wm + mf * 16 + quad * 4 + r;
                float a = (float)acc[mf][nf][r];
                if (EPI == 0) {
                    float v = rs[m] * a + bv;
                    v = 0.5f * v * (1.0f + erff(v * 0.70710678118654752f));
                    ((__bf16*)Cout)[(size_t)m * N + n] = (__bf16)v;
                } else {
                    float2 so = ((const float2*)rs)[m];
                    ((float*)Cout)[(size_t)m * N + n] = so.x * a + so.y * cs + bv;
                }
            }
    }
}

extern "C" void kernel_launch(void* const* d_in, const int* in_sizes, int n_in,
                              void* d_out, int out_size, void* d_ws, size_t ws_size,
                              hipStream_t stream) {
    const float* x  = (const float*)d_in[0];
    const float* w1 = (const float*)d_in[1];
    const float* b1 = (const float*)d_in[2];
    const float* w2 = (const float*)d_in[3];
    const float* b2 = (const float*)d_in[4];
    float* out = (float*)d_out;

    char* ws = (char*)d_ws;
    float*  thr = (float*)ws;
    float*  sx  = (float*)(ws + 256);
    float2* sh  = (float2*)(ws + 256 + (64 << 10));
    float*  colsum = (float*)(ws + 256 + (192 << 10));
    int8_t* xq  = (int8_t*)(ws + 256 + (256 << 10));
    int8_t* w1q = xq  + (size_t)MTOK * D_MODEL;
    int8_t* w2q = w1q + (size_t)D_FF * D_MODEL;
    int8_t* hq  = w2q + (size_t)D_MODEL * D_FF;
    __bf16* h   = (__bf16*)(hq + (size_t)MTOK * D_FF);
    double* partials = (double*)h;   // 16 KiB, consumed before h is written

    absum_s1<<<dim3(1024, 2), 256, 0, stream>>>(w1, w2, partials);
    absum_s2<<<1, 256, 0, stream>>>(partials, thr);

    quantw1<<<NW / 1024, 256, 0, stream>>>(w1, thr, w1q);
    quantw2<<<D_MODEL, 256, 0, stream>>>(w2, thr, w2q, colsum);
    xquant<<<MTOK, 256, 0, stream>>>(x, xq, sx);

    dim3 g1(D_FF / 128, MTOK / 256);     // (64, 64)
    gemm_i8_bt<0><<<g1, 256, 0, stream>>>(xq, w1q, b1, sx, nullptr, (void*)h,
                                          MTOK, D_FF, D_MODEL);

    hquant<<<MTOK, 256, 0, stream>>>(h, hq, sh);

    dim3 g2(D_MODEL / 128, MTOK / 256);  // (16, 64)
    gemm_i8_bt<1><<<g2, 256, 0, stream>>>(hq, w2q, b2, (const float*)sh, colsum, (void*)out,
                                          MTOK, D_MODEL, D_FF);
}

// Round 5
// 1094.319 us; speedup vs baseline: 1.0400x; 1.0400x over previous
//
#include <hip/hip_runtime.h>
#include <hip/hip_bf16.h>
#include <math.h>
#include <stdint.h>

#define D_MODEL 2048
#define D_FF    8192
#define MTOK    16384   // 4 * 4096 tokens
#define NW      (D_FF * D_MODEL)   // elements per weight matrix

typedef int    i32x4  __attribute__((ext_vector_type(4)));
typedef __bf16 bf16x8 __attribute__((ext_vector_type(8)));

// width-16 async global->LDS (per-lane global addr, wave-uniform LDS base + lane*16)
#define GLOAD_LDS16(gp, lp)                                                   \
  __builtin_amdgcn_global_load_lds(                                           \
      (__attribute__((address_space(1))) void*)(gp),                          \
      (__attribute__((address_space(3))) void*)(lp), 16, 0, 0)

// ---------------- stage 1: deterministic double partial sums of |w| ----------------
__global__ void absum_s1(const float* __restrict__ w1, const float* __restrict__ w2,
                         double* __restrict__ partials) {
    const float* w = blockIdx.y ? w2 : w1;
    __shared__ double sm[256];
    int tid = blockIdx.x * 256 + threadIdx.x;
    double s = 0.0;
    for (int i = tid; i < NW / 4; i += 1024 * 256) {
        float4 v = ((const float4*)w)[i];
        s += (double)fabsf(v.x) + (double)fabsf(v.y) + (double)fabsf(v.z) + (double)fabsf(v.w);
    }
    sm[threadIdx.x] = s;
    __syncthreads();
    for (int off = 128; off > 0; off >>= 1) {
        if (threadIdx.x < off) sm[threadIdx.x] += sm[threadIdx.x + off];
        __syncthreads();
    }
    if (threadIdx.x == 0) partials[blockIdx.y * 1024 + blockIdx.x] = sm[0];
}

// ---------------- stage 2: 1024 partials -> float threshold 0.7*mean ----------------
__global__ void absum_s2(const double* __restrict__ partials, float* __restrict__ thr) {
    __shared__ double sm[256];
    for (int wsel = 0; wsel < 2; ++wsel) {
        const double* p = partials + wsel * 1024;
        double s = p[threadIdx.x] + p[threadIdx.x + 256] + p[threadIdx.x + 512] + p[threadIdx.x + 768];
        sm[threadIdx.x] = s;
        __syncthreads();
        for (int off = 128; off > 0; off >>= 1) {
            if (threadIdx.x < off) sm[threadIdx.x] += sm[threadIdx.x + off];
            __syncthreads();
        }
        if (threadIdx.x == 0) thr[wsel] = (float)(0.7 * (sm[0] / (double)NW));
        __syncthreads();
    }
}

// ---------------- w1 -> ternary i8, elementwise ----------------
__global__ void quantw1(const float* __restrict__ w, const float* __restrict__ thr,
                        int8_t* __restrict__ q) {
    float t = thr[0];
    int i = (blockIdx.x * 256 + threadIdx.x) * 4;
    float4 v = *(const float4*)(w + i);
    char4 o;
    o.x = (fabsf(v.x) >= t) ? (v.x > 0.f ? 1 : -1) : 0;
    o.y = (fabsf(v.y) >= t) ? (v.y > 0.f ? 1 : -1) : 0;
    o.z = (fabsf(v.z) >= t) ? (v.z > 0.f ? 1 : -1) : 0;
    o.w = (fabsf(v.w) >= t) ? (v.w > 0.f ? 1 : -1) : 0;
    *(char4*)(q + i) = o;
}

// ---------------- w2 -> ternary i8, one block per row, + row sums (colsum) ---------
__global__ void quantw2(const float* __restrict__ w, const float* __restrict__ thr,
                        int8_t* __restrict__ q, float* __restrict__ colsum) {
    __shared__ int sm[256];
    float t = thr[1];
    const int row = blockIdx.x;
    const int tid = threadIdx.x;
    int isum = 0;
    #pragma unroll
    for (int j = 0; j < 8; ++j) {
        int idx = row * D_FF + j * 1024 + tid * 4;
        float4 v = *(const float4*)(w + idx);
        char4 o;
        o.x = (fabsf(v.x) >= t) ? (v.x > 0.f ? 1 : -1) : 0;
        o.y = (fabsf(v.y) >= t) ? (v.y > 0.f ? 1 : -1) : 0;
        o.z = (fabsf(v.z) >= t) ? (v.z > 0.f ? 1 : -1) : 0;
        o.w = (fabsf(v.w) >= t) ? (v.w > 0.f ? 1 : -1) : 0;
        isum += o.x + o.y + o.z + o.w;
        *(char4*)(q + idx) = o;
    }
    sm[tid] = isum;
    __syncthreads();
    for (int off = 128; off > 0; off >>= 1) {
        if (tid < off) sm[tid] += sm[tid + off];
        __syncthreads();
    }
    if (tid == 0) colsum[row] = (float)sm[0];
}

// ---------------- x -> per-row symmetric i8, one block per token row ----------------
__global__ void xquant(const float* __restrict__ x, int8_t* __restrict__ xq,
                       float* __restrict__ sx) {
    __shared__ float sm[256];
    const int row = blockIdx.x;
    const int tid = threadIdx.x;
    float4 v[2];
    float mx = 0.f;
    #pragma unroll
    for (int j = 0; j < 2; ++j) {
        v[j] = *(const float4*)(x + (size_t)row * D_MODEL + j * 1024 + tid * 4);
        mx = fmaxf(mx, fmaxf(fmaxf(fabsf(v[j].x), fabsf(v[j].y)),
                             fmaxf(fabsf(v[j].z), fabsf(v[j].w))));
    }
    sm[tid] = mx;
    __syncthreads();
    for (int off = 128; off > 0; off >>= 1) {
        if (tid < off) sm[tid] = fmaxf(sm[tid], sm[tid + off]);
        __syncthreads();
    }
    float m = sm[0];
    float inv = (m > 0.f) ? 127.f / m : 0.f;
    if (tid == 0) sx[row] = (m > 0.f) ? m / 127.f : 0.f;
    #pragma unroll
    for (int j = 0; j < 2; ++j) {
        char4 o;
        o.x = (int8_t)min(127, max(-127, __float2int_rn(v[j].x * inv)));
        o.y = (int8_t)min(127, max(-127, __float2int_rn(v[j].y * inv)));
        o.z = (int8_t)min(127, max(-127, __float2int_rn(v[j].z * inv)));
        o.w = (int8_t)min(127, max(-127, __float2int_rn(v[j].w * inv)));
        *(char4*)(xq + (size_t)row * D_MODEL + j * 1024 + tid * 4) = o;
    }
}

// ---------------- gelu(h) bf16 -> per-row ASYMMETRIC i8 (zero-point via colsum) -----
__global__ void hquant(const __bf16* __restrict__ h, int8_t* __restrict__ hq,
                       float2* __restrict__ sh) {
    __shared__ float sm[256];
    const int row = blockIdx.x;
    const int tid = threadIdx.x;
    const float gmin = -0.17f;
    float vals[4][8];
    float mx = -1e30f;
    #pragma unroll
    for (int j = 0; j < 4; ++j) {
        bf16x8 b = *(const bf16x8*)(h + (size_t)row * D_FF + j * 2048 + tid * 8);
        #pragma unroll
        for (int e = 0; e < 8; ++e) {
            float f = (float)b[e];
            vals[j][e] = f;
            mx = fmaxf(mx, f);
        }
    }
    sm[tid] = mx;
    __syncthreads();
    for (int off = 128; off > 0; off >>= 1) {
        if (tid < off) sm[tid] = fmaxf(sm[tid], sm[tid + off]);
        __syncthreads();
    }
    float M = sm[0];
    float s = (M - gmin) / 254.f;
    float inv = 254.f / (M - gmin);
    if (tid == 0) sh[row] = make_float2(s, 127.f * s + gmin);
    #pragma unroll
    for (int j = 0; j < 4; ++j) {
        char4 o0, o1;
        int q[8];
        #pragma unroll
        for (int e = 0; e < 8; ++e)
            q[e] = min(127, max(-127, __float2int_rn((vals[j][e] - gmin) * inv) - 127));
        o0.x = q[0]; o0.y = q[1]; o0.z = q[2]; o0.w = q[3];
        o1.x = q[4]; o1.y = q[5]; o1.z = q[6]; o1.w = q[7];
        int8_t* p = hq + (size_t)row * D_FF + j * 2048 + tid * 8;
        *(char4*)p = o0;
        *(char4*)(p + 4) = o1;
    }
}

// ===================================================================================
// 256x128 i8 MFMA GEMM — R2 skeleton (measured best: 427us, MfmaUtil 29%, occ 41%)
//   + R4's proven XCD-burst map (FETCH 557->237 MB) + rolling A-frag prefetch.
//   C = A[M,K] * B[N,K]^T ; 512 threads = 8 waves (4M x 2N), per-wave 64x64.
//   Ring-3 of 24 KiB stages = 72 KiB -> 2 blocks/CU; launch_bounds(512,4) -> 56 VGPR,
//   4 waves/SIMD (2 per block, cross-block overlap).
//   Convoy fix (R4 post-mortem): R2 drained all 8 frag reads before the 16-MFMA
//   cluster -> block-wide read-storm / MFMA-storm phases serialize the LDS and MFMA
//   pipes (both measured <35% busy). Now each 4-MFMA cluster issues the NEXT A-frag
//   ds_read first, so the wave itself overlaps read latency with MFMA (fine-grained
//   lgkmcnt instead of full drain).
//   Per half: 3 gloads/thread (stage s+2), counted s_waitcnt vmcnt(3), ONE s_barrier.
//   16B chunk c of row r stored at slot c^((r>>1)&3): frag reads 2-way = free.
// EPI==0 (fc1): h[m,n] = bf16( gelu( rs[m] * acc + bias[n] ) )
// EPI==1 (fc2): out = rs2[m].x * acc + rs2[m].y * colsum[n] + bias[n]
// Both: XCD-burst map — XCD owns 8 by-rows, 4-by bursts bx-major (B panel L2-reuse).
// ===================================================================================
template<int EPI>
__global__ __launch_bounds__(512, 4) void gemm_i8_bt(
    const int8_t* __restrict__ A,    // [M,K]
    const int8_t* __restrict__ B,    // [N,K]
    const float*  __restrict__ bias, // [N]
    const float*  __restrict__ rs,   // fc1: sx[M] ; fc2: (float2*)sh[M]
    const float*  __restrict__ colsum, // fc2 only: [N]
    void* __restrict__ Cout,
    int M, int N, int K)
{
    __shared__ int8_t Sh[3 * 24576];   // ring-3: per stage A[256][64] + B[128][64]

    const int tid  = threadIdx.x;
    const int wave = tid >> 6;
    const int lane = tid & 63;
    const int quad = lane >> 4;
    const int l15  = lane & 15;
    const int wm   = (wave >> 1) * 64;    // 4 wave-rows of M
    const int wn   = (wave & 1) * 64;     // 2 wave-cols of N

    // ---- block -> tile map: XCD x owns by in [x*8,x*8+8), 4-by bursts, bx-major ----
    const int gx   = gridDim.x;           // fc1: 64, fc2: 16
    const int orig = blockIdx.y * gx + blockIdx.x;
    const int xcd  = orig & 7;
    const int l    = orig >> 3;
    const int stsh = (EPI == 0) ? 8 : 6;  // log2(4*gx)
    const int st   = l >> stsh;           // supertile (2 per XCD)
    const int r    = l & ((1 << stsh) - 1);
    const int by   = xcd * 8 + st * 4 + (r & 3);
    const int bx   = r >> 2;
    const int m0 = by << 8;   // *256
    const int n0 = bx << 7;   // *128

    i32x4 acc[4][4] = {};

    // ---- staging: per K-half, A = 1024 chunks (2/thread), B = 512 (1/thread) ----
    const int row0 = tid >> 2;
    const int cg0  = (tid & 3) ^ ((row0 >> 1) & 3);   // same for row0 and row0+128
    const int8_t* gA0 = A + (size_t)(m0 + row0) * K + cg0 * 16;
    const int8_t* gA1 = gA0 + (size_t)128 * K;
    const int8_t* gB0 = B + (size_t)(n0 + row0) * K + cg0 * 16;
    char* const ldsb = (char*)Sh;
    char* const dA0  = ldsb + wave * 1024;            // + lane*16 by HW
    char* const dA1  = ldsb + 8192  + wave * 1024;
    char* const dB0  = ldsb + 16384 + wave * 1024;

    // ---- per-thread fragment LDS offsets (within a stage) ----
    int aoff[4], boff[4];
    #pragma unroll
    for (int f = 0; f < 4; ++f) {
        int ra = wm + f * 16 + l15;
        aoff[f] = ra * 64 + ((quad ^ ((ra >> 1) & 3)) << 4);
        int rb = wn + f * 16 + l15;
        boff[f] = 16384 + rb * 64 + ((quad ^ ((rb >> 1) & 3)) << 4);
    }

    const int NH = K >> 6;   // BK=64 halves (fc1: 32, fc2: 128)
    const int STG = 24576;

    // ---- prologue: stage halves 0,1 (6 loads/thread); wait half 0 ----
    #pragma unroll
    for (int h = 0; h < 2; ++h) {
        GLOAD_LDS16(gA0, dA0 + h * STG);
        GLOAD_LDS16(gA1, dA1 + h * STG);
        GLOAD_LDS16(gB0, dB0 + h * STG);
        gA0 += 64; gA1 += 64; gB0 += 64;
    }
    asm volatile("s_waitcnt vmcnt(3)" ::: "memory");
    __builtin_amdgcn_s_barrier();
    __builtin_amdgcn_sched_barrier(0);

    int roff = 0;             // stage being read   (s % 3) * STG
    int soff = 2 * STG;       // stage being filled ((s+2) % 3) * STG

    for (int s = 0; s < NH; ++s) {
        // issue next-next stage loads first (earliest HBM start)
        if (s + 2 < NH) {
            GLOAD_LDS16(gA0, ldsb + soff + (dA0 - ldsb));
            GLOAD_LDS16(gA1, ldsb + soff + (dA1 - ldsb));
            GLOAD_LDS16(gB0, ldsb + soff + (dB0 - ldsb));
            gA0 += 64; gA1 += 64; gB0 += 64;
        }
        // B frags + first A frag; then rolling prefetch of A frag mf+1 under the
        // 4-MFMA cluster of frag mf (wave-level read/MFMA overlap, no full drain).
        i32x4 bfr[4];
        #pragma unroll
        for (int f = 0; f < 4; ++f) bfr[f] = *(const i32x4*)(ldsb + roff + boff[f]);
        i32x4 a_cur = *(const i32x4*)(ldsb + roff + aoff[0]);
        __builtin_amdgcn_s_setprio(1);
        #pragma unroll
        for (int mf = 0; mf < 4; ++mf) {
            i32x4 a_nxt;
            if (mf < 3) a_nxt = *(const i32x4*)(ldsb + roff + aoff[mf + 1]);
            #pragma unroll
            for (int nf = 0; nf < 4; ++nf)
                acc[mf][nf] = __builtin_amdgcn_mfma_i32_16x16x64_i8(
                    a_cur, bfr[nf], acc[mf][nf], 0, 0, 0);
            a_cur = a_nxt;
        }
        __builtin_amdgcn_s_setprio(0);
        // counted boundary: stage s+1 must be landed; keep stage s+2 in flight
        if (s < NH - 2)       { asm volatile("s_waitcnt vmcnt(3)" ::: "memory"); }
        else if (s == NH - 2) { asm volatile("s_waitcnt vmcnt(0)" ::: "memory"); }
        __builtin_amdgcn_sched_barrier(0);
        __builtin_amdgcn_s_barrier();
        __builtin_amdgcn_sched_barrier(0);
        roff = (roff == 2 * STG) ? 0 : roff + STG;
        soff = (soff == 2 * STG) ? 0 : soff + STG;
    }

    // ---- epilogue: C/D layout col = lane&15, row = quad*4 + r ----
    #pragma unroll
    for (int nf = 0; nf < 4; ++nf) {
        const int n = n0 + wn + nf * 16 + l15;
        const float bv = bias[n];
        const float cs = (EPI == 1) ? colsum[n] : 0.f;
        #pragma unroll
        for (int mf = 0; mf < 4; ++mf)
            #pragma unroll
            for (int r = 0; r < 4; ++r) {
                int m = m0 + wm + mf * 16 + quad * 4 + r;
                float a = (float)acc[mf][nf][r];
                if (EPI == 0) {
                    float v = rs[m] * a + bv;
                    v = 0.5f * v * (1.0f + erff(v * 0.70710678118654752f));
                    ((__bf16*)Cout)[(size_t)m * N + n] = (__bf16)v;
                } else {
                    float2 so = ((const float2*)rs)[m];
                    ((float*)Cout)[(size_t)m * N + n] = so.x * a + so.y * cs + bv;
                }
            }
    }
}

extern "C" void kernel_launch(void* const* d_in, const int* in_sizes, int n_in,
                              void* d_out, int out_size, void* d_ws, size_t ws_size,
                              hipStream_t stream) {
    const float* x  = (const float*)d_in[0];
    const float* w1 = (const float*)d_in[1];
    const float* b1 = (const float*)d_in[2];
    const float* w2 = (const float*)d_in[3];
    const float* b2 = (const float*)d_in[4];
    float* out = (float*)d_out;

    char* ws = (char*)d_ws;
    float*  thr = (float*)ws;
    float*  sx  = (float*)(ws + 256);
    float2* sh  = (float2*)(ws + 256 + (64 << 10));
    float*  colsum = (float*)(ws + 256 + (192 << 10));
    int8_t* xq  = (int8_t*)(ws + 256 + (256 << 10));
    int8_t* w1q = xq  + (size_t)MTOK * D_MODEL;
    int8_t* w2q = w1q + (size_t)D_FF * D_MODEL;
    int8_t* hq  = w2q + (size_t)D_MODEL * D_FF;
    __bf16* h   = (__bf16*)(hq + (size_t)MTOK * D_FF);
    double* partials = (double*)h;   // 16 KiB, consumed before h is written

    absum_s1<<<dim3(1024, 2), 256, 0, stream>>>(w1, w2, partials);
    absum_s2<<<1, 256, 0, stream>>>(partials, thr);

    quantw1<<<NW / 1024, 256, 0, stream>>>(w1, thr, w1q);
    quantw2<<<D_MODEL, 256, 0, stream>>>(w2, thr, w2q, colsum);
    xquant<<<MTOK, 256, 0, stream>>>(x, xq, sx);

    dim3 g1(D_FF / 128, MTOK / 256);     // (64, 64)
    gemm_i8_bt<0><<<g1, 512, 0, stream>>>(xq, w1q, b1, sx, nullptr, (void*)h,
                                          MTOK, D_FF, D_MODEL);

    hquant<<<MTOK, 256, 0, stream>>>(h, hq, sh);

    dim3 g2(D_MODEL / 128, MTOK / 256);  // (16, 64)
    gemm_i8_bt<1><<<g2, 512, 0, stream>>>(hq, w2q, b2, (const float*)sh, colsum, (void*)out,
                                          MTOK, D_MODEL, D_FF);
}